// Round 1
// baseline (232.532 us; speedup 1.0000x reference)
//
#include <hip/hip_runtime.h>
#include <math.h>

#define DIM 1024

// Native clang vector type — __builtin_nontemporal_load/store require a
// scalar or native vector, not HIP_vector_type<float,4>.
typedef float vfloat4 __attribute__((ext_vector_type(4)));

// Fused kernel: every block redundantly computes
//   mask = DIM * softmax(mask_param) * _mask          (1024 channels)
// then applies its grid-stride slice of out = x * mask (float4-vectorized,
// nontemporal: x/out are streamed exactly once, keep them out of L2).
// Block 0 additionally writes the mask to the second output slot.
//
// blocks=2048: 8 blocks/CU x 256 CU, 4 waves/block -> 32 waves/CU, full
// occupancy in one dispatch round; 4096 float4/block (64 KB streamed) vs
// ~8 KB redundant softmax traffic.
//
// R1 change: 4x-unrolled streaming loop — 4 independent nontemporal loads
// in flight before the dependent stores (MLP 1 -> 4 per wave).
__global__ __launch_bounds__(256) void fused_mask_mul_kernel(
    const vfloat4* __restrict__ x,
    const vfloat4* __restrict__ mask_param4,  // 256 float4 = 1024 floats
    const vfloat4* __restrict__ mask_in4,     // 256 float4
    vfloat4* __restrict__ out,
    vfloat4* __restrict__ mask_out4,          // 256 float4 (output 1)
    int n4)
{
    const int t = threadIdx.x;               // 0..255

    // ---- per-block softmax over 1024 channels (thread t owns 4t..4t+3) ----
    const vfloat4 p = mask_param4[t];

    float m = fmaxf(fmaxf(p.x, p.y), fmaxf(p.z, p.w));
    #pragma unroll
    for (int o = 32; o > 0; o >>= 1) m = fmaxf(m, __shfl_down(m, o, 64));
    __shared__ float red[4];
    __shared__ float s_max, s_sum;
    if ((t & 63) == 0) red[t >> 6] = m;
    __syncthreads();
    if (t == 0) s_max = fmaxf(fmaxf(red[0], red[1]), fmaxf(red[2], red[3]));
    __syncthreads();

    const float mx = s_max;
    vfloat4 e;
    e.x = __expf(p.x - mx); e.y = __expf(p.y - mx);
    e.z = __expf(p.z - mx); e.w = __expf(p.w - mx);

    float s = e.x + e.y + e.z + e.w;
    #pragma unroll
    for (int o = 32; o > 0; o >>= 1) s += __shfl_down(s, o, 64);
    if ((t & 63) == 0) red[t >> 6] = s;
    __syncthreads();
    if (t == 0) s_sum = red[0] + red[1] + red[2] + red[3];
    __syncthreads();

    const float scale = (float)DIM / s_sum;  // PRUNE_RATE = 1.0
    const vfloat4 mi = mask_in4[t];
    vfloat4 mv = e * scale * mi;

    if (blockIdx.x == 0) mask_out4[t] = mv;

    // ---- grid-stride broadcast multiply, nontemporal, 4x unrolled ----
    const int idx    = blockIdx.x * 256 + t;
    const int stride = gridDim.x * 256;      // multiple of 256 -> mask invariant
    int i = idx;
    for (; i + 3 * stride < n4; i += 4 * stride) {
        vfloat4 v0 = __builtin_nontemporal_load(&x[i]);
        vfloat4 v1 = __builtin_nontemporal_load(&x[i + stride]);
        vfloat4 v2 = __builtin_nontemporal_load(&x[i + 2 * stride]);
        vfloat4 v3 = __builtin_nontemporal_load(&x[i + 3 * stride]);
        v0 *= mv; v1 *= mv; v2 *= mv; v3 *= mv;
        __builtin_nontemporal_store(v0, &out[i]);
        __builtin_nontemporal_store(v1, &out[i + stride]);
        __builtin_nontemporal_store(v2, &out[i + 2 * stride]);
        __builtin_nontemporal_store(v3, &out[i + 3 * stride]);
    }
    for (; i < n4; i += stride) {
        vfloat4 v = __builtin_nontemporal_load(&x[i]);
        v *= mv;
        __builtin_nontemporal_store(v, &out[i]);
    }
}

extern "C" void kernel_launch(void* const* d_in, const int* in_sizes, int n_in,
                              void* d_out, int out_size, void* d_ws, size_t ws_size,
                              hipStream_t stream)
{
    const float* x          = (const float*)d_in[0];   // [8,4096,1024] fp32
    const float* mask_param = (const float*)d_in[1];   // [1024] fp32
    const float* mask_in    = (const float*)d_in[2];   // [1024] fp32 (ones)

    const int n = in_sizes[0];                         // 33554432
    float* out_xm   = (float*)d_out;                   // output 0
    float* out_mask = (float*)d_out + n;               // output 1 (1024 floats)

    const int n4 = n / 4;                              // 8388608
    const int blocks = 2048;                           // 16 float4 per thread
    fused_mask_mul_kernel<<<blocks, 256, 0, stream>>>(
        (const vfloat4*)x, (const vfloat4*)mask_param, (const vfloat4*)mask_in,
        (vfloat4*)out_xm, (vfloat4*)out_mask, n4);
}

// Round 2
// 226.109 us; speedup vs baseline: 1.0284x; 1.0284x over previous
//
#include <hip/hip_runtime.h>
#include <math.h>

#define DIM 1024

// Native clang vector type — __builtin_nontemporal_load/store require a
// scalar or native vector, not HIP_vector_type<float,4>.
typedef float vfloat4 __attribute__((ext_vector_type(4)));

// Fused kernel: every block redundantly computes
//   mask = DIM * softmax(mask_param) * _mask          (1024 channels)
// then applies its grid-stride slice of out = x * mask (float4-vectorized,
// nontemporal: x/out are streamed exactly once, keep them out of L2).
// Block 0 additionally writes the mask to the second output slot.
//
// R2 changes:
//  - reverted the 4x unroll (R1: 226.1 -> 232.5 regression; streaming loop
//    is TLP-covered at 32 waves/CU, unroll only added tail overhead).
//  - barrier-free softmax prologue: each WAVE redundantly computes the full
//    1024-channel softmax via __shfl_xor butterflies (lane l reads the 4
//    float4 columns l, l+64, l+128, l+192 -> whole array per wave). No LDS,
//    no __syncthreads -> the compiler is free to overlap the first x loads
//    with the prologue, and blocks start streaming immediately.
__global__ __launch_bounds__(256) void fused_mask_mul_kernel(
    const vfloat4* __restrict__ x,
    const vfloat4* __restrict__ mask_param4,  // 256 float4 = 1024 floats
    const vfloat4* __restrict__ mask_in4,     // 256 float4
    vfloat4* __restrict__ out,
    vfloat4* __restrict__ mask_out4,          // 256 float4 (output 1)
    int n4)
{
    const int t = threadIdx.x;               // 0..255
    const int l = t & 63;                    // lane
    const int w = t >> 6;                    // wave id in block

    // ---- wave-redundant softmax over 1024 channels, shuffle-only ----
    // Each lane reads 4 float4 columns: l, l+64, l+128, l+192.
    const vfloat4 q0 = mask_param4[l];
    const vfloat4 q1 = mask_param4[l + 64];
    const vfloat4 q2 = mask_param4[l + 128];
    const vfloat4 q3 = mask_param4[l + 192];

    float m = fmaxf(fmaxf(q0.x, q0.y), fmaxf(q0.z, q0.w));
    m = fmaxf(m, fmaxf(fmaxf(q1.x, q1.y), fmaxf(q1.z, q1.w)));
    m = fmaxf(m, fmaxf(fmaxf(q2.x, q2.y), fmaxf(q2.z, q2.w)));
    m = fmaxf(m, fmaxf(fmaxf(q3.x, q3.y), fmaxf(q3.z, q3.w)));
    #pragma unroll
    for (int o = 32; o > 0; o >>= 1) m = fmaxf(m, __shfl_xor(m, o, 64));

    vfloat4 e0, e1, e2, e3;
    e0.x = __expf(q0.x - m); e0.y = __expf(q0.y - m);
    e0.z = __expf(q0.z - m); e0.w = __expf(q0.w - m);
    e1.x = __expf(q1.x - m); e1.y = __expf(q1.y - m);
    e1.z = __expf(q1.z - m); e1.w = __expf(q1.w - m);
    e2.x = __expf(q2.x - m); e2.y = __expf(q2.y - m);
    e2.z = __expf(q2.z - m); e2.w = __expf(q2.w - m);
    e3.x = __expf(q3.x - m); e3.y = __expf(q3.y - m);
    e3.z = __expf(q3.z - m); e3.w = __expf(q3.w - m);

    float s = (e0.x + e0.y + e0.z + e0.w) + (e1.x + e1.y + e1.z + e1.w)
            + (e2.x + e2.y + e2.z + e2.w) + (e3.x + e3.y + e3.z + e3.w);
    #pragma unroll
    for (int o = 32; o > 0; o >>= 1) s += __shfl_xor(s, o, 64);

    const float scale = (float)DIM / s;      // PRUNE_RATE = 1.0

    // Thread t's own channels (4t..4t+3) are column t = l + 64*w -> e{w}.
    // w is wave-uniform; static select chain (no runtime array index).
    vfloat4 esel = (w == 0) ? e0 : (w == 1) ? e1 : (w == 2) ? e2 : e3;
    const vfloat4 mi = mask_in4[t];
    vfloat4 mv = esel * scale * mi;

    if (blockIdx.x == 0) mask_out4[t] = mv;

    // ---- grid-stride broadcast multiply, nontemporal ----
    const int idx    = blockIdx.x * 256 + t;
    const int stride = gridDim.x * 256;      // multiple of 256 -> mask invariant
    for (int i = idx; i < n4; i += stride) {
        vfloat4 v = __builtin_nontemporal_load(&x[i]);
        v *= mv;
        __builtin_nontemporal_store(v, &out[i]);
    }
}

extern "C" void kernel_launch(void* const* d_in, const int* in_sizes, int n_in,
                              void* d_out, int out_size, void* d_ws, size_t ws_size,
                              hipStream_t stream)
{
    const float* x          = (const float*)d_in[0];   // [8,4096,1024] fp32
    const float* mask_param = (const float*)d_in[1];   // [1024] fp32
    const float* mask_in    = (const float*)d_in[2];   // [1024] fp32 (ones)

    const int n = in_sizes[0];                         // 33554432
    float* out_xm   = (float*)d_out;                   // output 0
    float* out_mask = (float*)d_out + n;               // output 1 (1024 floats)

    const int n4 = n / 4;                              // 8388608
    const int blocks = 2048;                           // 16 float4 per thread
    fused_mask_mul_kernel<<<blocks, 256, 0, stream>>>(
        (const vfloat4*)x, (const vfloat4*)mask_param, (const vfloat4*)mask_in,
        (vfloat4*)out_xm, (vfloat4*)out_mask, n4);
}